// Round 4
// baseline (1608.234 us; speedup 1.0000x reference)
//
#include <hip/hip_runtime.h>

// Problem constants
#define B_N   16384
#define OBS_N 256
#define T_N   16
#define H_N   512
#define A_N   16

typedef __attribute__((ext_vector_type(8))) short  bf16x8;
typedef __attribute__((ext_vector_type(4))) float  f32x4;

// ---- workspace layout ----
// [0,64): counts | [1024, 1024+1MB): idx lists | [2MB, 2MB+48MB): packed weights
#define IDX_OFF   1024
#define W_PK_OFF  (2u * 1024u * 1024u)
// Packed elements per task (hi+lo interleaved per 1024-elem tile):
//   A0: 256 tiles, A1: 512, C0: 256, C1: 512  (tile = 512 hi + 512 lo bf16)
#define PK_A0     0
#define PK_A1     262144
#define PK_C0     786432
#define PK_C1     1048576
#define PK_TASK   1572864
#define WS_NEED   ((size_t)W_PK_OFF + (size_t)T_N * PK_TASK * 2u)   // 52,428,800 B

__device__ __forceinline__ unsigned short f2bf(float x) {
    unsigned u = __float_as_uint(x);
    u += 0x7FFFu + ((u >> 16) & 1u);
    return (unsigned short)(u >> 16);
}
__device__ __forceinline__ float bf2f(unsigned short h) {
    return __uint_as_float(((unsigned)h) << 16);
}
__device__ __forceinline__ float tanh_fast(float v) {
    return 1.0f - 2.0f / (__expf(2.0f * v) + 1.0f);
}

// ---------------------------------------------------------------------------
// Binning: sample indices by task.
// ---------------------------------------------------------------------------
__global__ void bin_kernel(const int* __restrict__ task_ids,
                           int* __restrict__ counts,
                           int* __restrict__ idx)
{
    int b = blockIdx.x * blockDim.x + threadIdx.x;
    if (b < B_N) {
        int t = task_ids[b];
        int p = atomicAdd(&counts[t], 1);
        idx[t * B_N + p] = b;
    }
}

// ---------------------------------------------------------------------------
// Weight conversion+pack: [T][K][512] f32 -> per-(16n x 32k) MFMA tiles.
// Tile tt = nt*(K/32)+ks holds 1024 bf16: [512 hi][512 lo], element order
// lane*8+j with lane = (n&15) + 16*((k&31)>>3), j = k&7 — exactly the
// 16x16x32 B-fragment order, so GEMM loads are 1 coalesced dwordx4 per frag.
// Block = one (task, seg, ks): stages 32x512 f32 (64 KB LDS), packs 32 tiles.
// ---------------------------------------------------------------------------
__global__ __launch_bounds__(256)
void conv_pack(const float* __restrict__ aW0, const float* __restrict__ aW1,
               const float* __restrict__ cW0, const float* __restrict__ cW1,
               unsigned short* __restrict__ wp)
{
    __shared__ float sf[32 * 512];
    const int bid = blockIdx.x;              // 16 tasks * 48
    const int t = bid / 48, s = bid % 48;
    const float* src; int K, ks, pk;
    if (s < 8)       { src = aW0; K = 256; ks = s;      pk = PK_A0; }
    else if (s < 24) { src = aW1; K = 512; ks = s - 8;  pk = PK_A1; }
    else if (s < 32) { src = cW0; K = 256; ks = s - 24; pk = PK_C0; }
    else             { src = cW1; K = 512; ks = s - 32; pk = PK_C1; }

    const int tid = threadIdx.x;
    // stage 32 k-rows (contiguous 64 KB) coalesced
    const float* sp = src + ((size_t)t * K + (size_t)ks * 32) * 512;
    #pragma unroll
    for (int i = 0; i < 16; ++i) {
        int f = tid + i * 256;               // 4096 float4
        *(float4*)(sf + f * 4) = *(const float4*)(sp + f * 4);
    }
    __syncthreads();

    unsigned short* wt = wp + (size_t)t * PK_TASK + pk;
    const int KS = K / 32;
    #pragma unroll
    for (int u = 0; u < 8; ++u) {
        int p    = u * 256 + tid;            // (nt, lane) pairs: 32*64
        int nt   = p >> 6;
        int lane = p & 63;
        int ln   = lane & 15;
        int ko   = (lane >> 4) * 8;
        unsigned hi2[4], lo2[4];
        #pragma unroll
        for (int jj = 0; jj < 4; ++jj) {
            float v0 = sf[(ko + 2 * jj + 0) * 512 + nt * 16 + ln];
            float v1 = sf[(ko + 2 * jj + 1) * 512 + nt * 16 + ln];
            unsigned short h0 = f2bf(v0), h1 = f2bf(v1);
            unsigned short l0 = f2bf(v0 - bf2f(h0));
            unsigned short l1 = f2bf(v1 - bf2f(h1));
            hi2[jj] = (unsigned)h0 | ((unsigned)h1 << 16);
            lo2[jj] = (unsigned)l0 | ((unsigned)l1 << 16);
        }
        size_t base = (size_t)(nt * KS + ks) * 1024 + lane * 8;
        *(uint4*)(wt + base)       = make_uint4(hi2[0], hi2[1], hi2[2], hi2[3]);
        *(uint4*)(wt + base + 512) = make_uint4(lo2[0], lo2[1], lo2[2], lo2[3]);
    }
}

// ---------------------------------------------------------------------------
// GEMM tile engine. Block 512 thr (8 waves), 64 rows x 512 cols.
// Wave w owns cols [w*64, w*64+64) = tiles nt = w*4..w*4+3.
// A (activations) hi/lo in LDS, XOR-swizzled (byte ^= (row&7)<<4).
// B (weights) streamed coalesced from packed global, double-buffered.
// Split product: C += Ah*Bh + Ah*Bl + Al*Bh.
// ---------------------------------------------------------------------------
#define GEMM_STEP(S, CH, CL, NH, NL) do {                                      \
    const int sp_ = ((S) + 1 < KS) ? (S) + 1 : (S);                            \
    _Pragma("unroll")                                                          \
    for (int ct = 0; ct < 4; ++ct) {                                           \
        const unsigned short* q_ = bp + (size_t)(ct * KS + sp_) * 1024;        \
        NH[ct] = *(const bf16x8*)q_;                                           \
        NL[ct] = *(const bf16x8*)(q_ + 512);                                   \
    }                                                                          \
    bf16x8 ah_[4], al_[4];                                                     \
    _Pragma("unroll")                                                          \
    for (int m = 0; m < 4; ++m) {                                              \
        int ab_ = (abase[m] + (S) * 64) ^ swz;                                 \
        ah_[m] = *(const bf16x8*)(ahb + ab_);                                  \
        al_[m] = *(const bf16x8*)(alb + ab_);                                  \
    }                                                                          \
    _Pragma("unroll")                                                          \
    for (int m = 0; m < 4; ++m)                                                \
    _Pragma("unroll")                                                          \
    for (int ct = 0; ct < 4; ++ct) {                                           \
        acc[m][ct] = __builtin_amdgcn_mfma_f32_16x16x32_bf16(ah_[m], CH[ct], acc[m][ct], 0, 0, 0); \
        acc[m][ct] = __builtin_amdgcn_mfma_f32_16x16x32_bf16(ah_[m], CL[ct], acc[m][ct], 0, 0, 0); \
        acc[m][ct] = __builtin_amdgcn_mfma_f32_16x16x32_bf16(al_[m], CH[ct], acc[m][ct], 0, 0, 0); \
    }                                                                          \
} while (0)

template <int K>
__device__ __forceinline__ void gemm_tiles(const unsigned short* __restrict__ wseg,
                                           const char* __restrict__ ahb,
                                           const char* __restrict__ alb,
                                           int w, int lane, f32x4 acc[4][4])
{
    constexpr int KS = K / 32;
    const int ln  = lane & 15;
    const int lk  = (lane >> 4) * 8;
    const int swz = (ln & 7) << 4;
    const unsigned short* bp = wseg + (size_t)(w * 4) * KS * 1024 + lane * 8;

    int abase[4];
    #pragma unroll
    for (int m = 0; m < 4; ++m)
        abase[m] = ((m * 16 + ln) * K + lk) * 2;

    bf16x8 bhA[4], blA[4], bhB[4], blB[4];
    #pragma unroll
    for (int ct = 0; ct < 4; ++ct) {
        const unsigned short* q = bp + (size_t)(ct * KS) * 1024;
        bhA[ct] = *(const bf16x8*)q;
        blA[ct] = *(const bf16x8*)(q + 512);
    }
    #pragma unroll
    for (int s = 0; s < KS; s += 2) {
        GEMM_STEP(s,     bhA, blA, bhB, blB);
        GEMM_STEP(s + 1, bhB, blB, bhA, blA);
    }
}

__device__ __forceinline__ void zero_acc(f32x4 acc[4][4]) {
#pragma unroll
    for (int m = 0; m < 4; ++m)
#pragma unroll
        for (int ct = 0; ct < 4; ++ct)
            acc[m][ct] = (f32x4){0.f, 0.f, 0.f, 0.f};
}

// epilogue: tanh + split-bf16 -> next A LDS ([64][512] hi/lo, swizzled)
__device__ __forceinline__ void epi_tanh(f32x4 acc[4][4], const float* __restrict__ bias,
                                         char* ahb, char* alb, int w, int lane)
{
    const int q4 = (lane >> 4) * 4;
    const int ln = lane & 15;
#pragma unroll
    for (int ct = 0; ct < 4; ++ct) {
        int col = w * 64 + ct * 16 + ln;
        float b = bias[col];
#pragma unroll
        for (int m = 0; m < 4; ++m) {
#pragma unroll
            for (int q = 0; q < 4; ++q) {
                int row = m * 16 + q4 + q;
                float t = tanh_fast(acc[m][ct][q] + b);
                unsigned short h = f2bf(t);
                unsigned short l = f2bf(t - bf2f(h));
                int byte = ((row * 512 + col) * 2) ^ ((row & 7) << 4);
                *(unsigned short*)(ahb + byte) = h;
                *(unsigned short*)(alb + byte) = l;
            }
        }
    }
}

// epilogue: tanh -> fp32 h2 LDS ([64][512] f32, swizzled)
__device__ __forceinline__ void epi_h2(f32x4 acc[4][4], const float* __restrict__ bias,
                                       char* h2b, int w, int lane)
{
    const int q4 = (lane >> 4) * 4;
    const int ln = lane & 15;
#pragma unroll
    for (int ct = 0; ct < 4; ++ct) {
        int col = w * 64 + ct * 16 + ln;
        float b = bias[col];
#pragma unroll
        for (int m = 0; m < 4; ++m) {
#pragma unroll
            for (int q = 0; q < 4; ++q) {
                int row = m * 16 + q4 + q;
                float t = tanh_fast(acc[m][ct][q] + b);
                int byte = (row * 2048 + col * 4) ^ ((row & 7) << 4);
                *(float*)(h2b + byte) = t;
            }
        }
    }
}

// gather x rows -> xs hi/lo ([64][256] bf16, swizzled); 1 KB coalesced per instr
__device__ __forceinline__ void gather_xs(const float* __restrict__ x,
                                          const int* __restrict__ tidx_lds, int nrows,
                                          char* xhb, char* xlb, int tid)
{
#pragma unroll
    for (int kk = 0; kk < 8; ++kk) {
        int f   = tid + kk * 512;
        int row = f >> 6;
        int c4  = f & 63;
        int rr  = min(row, nrows - 1);
        int sid = tidx_lds[rr];
        float4 v = *(const float4*)(x + (size_t)sid * OBS_N + c4 * 4);
        unsigned short h0 = f2bf(v.x), h1 = f2bf(v.y), h2e = f2bf(v.z), h3 = f2bf(v.w);
        unsigned short l0 = f2bf(v.x - bf2f(h0)), l1 = f2bf(v.y - bf2f(h1));
        unsigned short l2 = f2bf(v.z - bf2f(h2e)), l3 = f2bf(v.w - bf2f(h3));
        uint2 hp = make_uint2((unsigned)h0 | ((unsigned)h1 << 16), (unsigned)h2e | ((unsigned)h3 << 16));
        uint2 lp = make_uint2((unsigned)l0 | ((unsigned)l1 << 16), (unsigned)l2 | ((unsigned)l3 << 16));
        int byte = ((row * OBS_N + c4 * 4) * 2) ^ ((row & 7) << 4);
        *(uint2*)(xhb + byte) = hp;
        *(uint2*)(xlb + byte) = lp;
    }
}

__device__ __forceinline__ void actor_head(const char* __restrict__ h2b,
                                           const float* __restrict__ W2,
                                           const float* __restrict__ b2,
                                           const int* __restrict__ tidx_lds, int nrows,
                                           float* __restrict__ out, int tid)
{
#pragma unroll
    for (int oo = 0; oo < 2; ++oo) {
        int o = tid + oo * 512;
        int r = o >> 4, a = o & 15;
        float acc = 0.f;
#pragma unroll 4
        for (int i = 0; i < H_N; i += 4) {
            int byte = (r * 2048 + i * 4) ^ ((r & 7) << 4);
            float4 hv = *(const float4*)(h2b + byte);
            acc = fmaf(hv.x, W2[(i + 0) * A_N + a], acc);
            acc = fmaf(hv.y, W2[(i + 1) * A_N + a], acc);
            acc = fmaf(hv.z, W2[(i + 2) * A_N + a], acc);
            acc = fmaf(hv.w, W2[(i + 3) * A_N + a], acc);
        }
        if (r < nrows)
            out[(size_t)tidx_lds[r] * A_N + a] = acc + b2[a];
    }
}

// critic head: lane stripe i = sub*4 + j*32 -> 8 subs x 4 banks = all 32 banks
__device__ __forceinline__ void critic_head(const char* __restrict__ h2b,
                                            const float* __restrict__ W2, float b2,
                                            const int* __restrict__ tidx_lds, int nrows,
                                            float* __restrict__ out, int tid)
{
    int r = tid >> 3, sub = tid & 7;
    float acc = 0.f;
#pragma unroll
    for (int j = 0; j < 16; ++j) {
        int i = sub * 4 + j * 32;
        int byte = (r * 2048 + i * 4) ^ ((r & 7) << 4);
        float4 hv = *(const float4*)(h2b + byte);
        float4 wv = *(const float4*)(W2 + i);
        acc = fmaf(hv.x, wv.x, acc);
        acc = fmaf(hv.y, wv.y, acc);
        acc = fmaf(hv.z, wv.z, acc);
        acc = fmaf(hv.w, wv.w, acc);
    }
    acc += __shfl_xor(acc, 1);
    acc += __shfl_xor(acc, 2);
    acc += __shfl_xor(acc, 4);
    if (sub == 0 && r < nrows)
        out[B_N * A_N + tidx_lds[r]] = acc + b2;
}

// LDS map (dynamic, 131,584 B):
//   [0,128K): union { xs_hi/h_hi | h2 f32 } with lo halves at +64K
//   [128K,+256): tidx
__global__ __launch_bounds__(512)
void moe_mfma_kernel(const float* __restrict__ x,
                     const int* __restrict__ counts,
                     const int* __restrict__ idx,
                     const unsigned short* __restrict__ wp,
                     const float* __restrict__ ab0, const float* __restrict__ ab1,
                     const float* __restrict__ aW2, const float* __restrict__ ab2,
                     const float* __restrict__ cb0, const float* __restrict__ cb1,
                     const float* __restrict__ cW2, const float* __restrict__ cb2,
                     float* __restrict__ out)
{
    extern __shared__ char lds[];
    char* lo_half  = lds + 65536;
    int*  tidx_lds = (int*)(lds + 131072);

    const int bx   = blockIdx.x;
    const int task = bx & 15;
    const int slot = bx >> 4;               // 16 slots x 64 rows = 1024/sweep
    const int cnt  = counts[task];
    const int tid  = threadIdx.x;
    const int w    = tid >> 6;
    const int lane = tid & 63;

    const unsigned short* wt = wp + (size_t)task * PK_TASK;

    for (int r0 = slot * 64; r0 < cnt; r0 += 1024) {
        int nrows = min(64, cnt - r0);

        __syncthreads();                     // protect tidx/h2 across iters
        if (tid < 64) {
            int rr = min(tid, nrows - 1);
            tidx_lds[tid] = idx[task * B_N + r0 + rr];
        }
        __syncthreads();

        f32x4 acc[4][4];

        // ================= ACTOR =================
        gather_xs(x, tidx_lds, nrows, lds, lo_half, tid);
        __syncthreads();
        zero_acc(acc);
        gemm_tiles<256>(wt + PK_A0, lds, lo_half, w, lane, acc);
        __syncthreads();                     // all waves done reading xs
        epi_tanh(acc, ab0 + task * H_N, lds, lo_half, w, lane);
        __syncthreads();
        zero_acc(acc);
        gemm_tiles<512>(wt + PK_A1, lds, lo_half, w, lane, acc);
        __syncthreads();                     // done reading h
        epi_h2(acc, ab1 + task * H_N, lds, w, lane);
        __syncthreads();
        actor_head(lds, aW2 + (size_t)task * H_N * A_N, ab2 + task * A_N,
                   tidx_lds, nrows, out, tid);
        __syncthreads();                     // heads done reading h2

        // ================= CRITIC =================
        gather_xs(x, tidx_lds, nrows, lds, lo_half, tid);
        __syncthreads();
        zero_acc(acc);
        gemm_tiles<256>(wt + PK_C0, lds, lo_half, w, lane, acc);
        __syncthreads();
        epi_tanh(acc, cb0 + task * H_N, lds, lo_half, w, lane);
        __syncthreads();
        zero_acc(acc);
        gemm_tiles<512>(wt + PK_C1, lds, lo_half, w, lane, acc);
        __syncthreads();
        epi_h2(acc, cb1 + task * H_N, lds, w, lane);
        __syncthreads();
        critic_head(lds, cW2 + (size_t)task * H_N, cb2[task],
                    tidx_lds, nrows, out, tid);
    }
}

// ===========================================================================
// Fallback (fp32 VALU) if ws_size can't hold packed weights.
// ===========================================================================
#define ROWS 16
template <int IN, bool TANH>
__device__ __forceinline__ void layer_block(const float* __restrict__ in_lds,
                                            const float* __restrict__ W,
                                            const float* __restrict__ bias,
                                            float* __restrict__ out_lds,
                                            int w, int lane)
{
#pragma unroll
    for (int cgi = 0; cgi < 2; ++cgi) {
        const int c = (w + 4 * cgi) * 64 + lane;
        float acc[ROWS];
#pragma unroll
        for (int r = 0; r < ROWS; ++r) acc[r] = 0.0f;
        const float* Wc = W + c;
#pragma unroll 2
        for (int i = 0; i < IN; i += 4) {
            float w0 = Wc[(i + 0) * H_N];
            float w1 = Wc[(i + 1) * H_N];
            float w2 = Wc[(i + 2) * H_N];
            float w3 = Wc[(i + 3) * H_N];
#pragma unroll
            for (int r = 0; r < ROWS; ++r) {
                float4 xv = *reinterpret_cast<const float4*>(&in_lds[r * IN + i]);
                acc[r] = fmaf(xv.x, w0, acc[r]);
                acc[r] = fmaf(xv.y, w1, acc[r]);
                acc[r] = fmaf(xv.z, w2, acc[r]);
                acc[r] = fmaf(xv.w, w3, acc[r]);
            }
        }
        float bb = bias[c];
#pragma unroll
        for (int r = 0; r < ROWS; ++r) {
            float v = acc[r] + bb;
            if (TANH) v = 1.0f - 2.0f / (__expf(2.0f * v) + 1.0f);
            out_lds[r * H_N + c] = v;
        }
    }
}

__global__ __launch_bounds__(256, 2)
void mlp_fallback(const float* __restrict__ x,
                  const int* __restrict__ counts,
                  const int* __restrict__ idx,
                  const float* __restrict__ aW0, const float* __restrict__ ab0,
                  const float* __restrict__ aW1, const float* __restrict__ ab1,
                  const float* __restrict__ aW2, const float* __restrict__ ab2,
                  const float* __restrict__ cW0, const float* __restrict__ cb0,
                  const float* __restrict__ cW1, const float* __restrict__ cb1,
                  const float* __restrict__ cW2, const float* __restrict__ cb2,
                  float* __restrict__ out)
{
    extern __shared__ float flds[];
    float* xs  = flds;
    float* hb0 = flds + ROWS * OBS_N;
    float* hb1 = hb0 + ROWS * H_N;

    const int bx    = blockIdx.x;
    const int phase = bx >> 11;
    const int task  = (bx & 7) + (phase << 3);
    const int tile  = (bx >> 3) & 255;
    const int cnt   = counts[task];
    const int r0    = tile * ROWS;
    if (r0 >= cnt) return;
    const int nrows = min(ROWS, cnt - r0);
    const int tid   = threadIdx.x;
    const int lane  = tid & 63;
    const int w     = tid >> 6;
    const int* tidx = idx + task * B_N + r0;

    {
        const float4* x4  = reinterpret_cast<const float4*>(x);
        float4*       xs4 = reinterpret_cast<float4*>(xs);
#pragma unroll
        for (int k = 0; k < 4; ++k) {
            int f = tid + k * 256;
            int r = f >> 6, c4 = f & 63;
            int rr = (r < nrows) ? r : (nrows - 1);
            xs4[f] = x4[(size_t)tidx[rr] * (OBS_N / 4) + c4];
        }
    }
    __syncthreads();
    layer_block<OBS_N, true>(xs,  aW0 + task * OBS_N * H_N, ab0 + task * H_N, hb0, w, lane);
    __syncthreads();
    layer_block<H_N,  true>(hb0, aW1 + task * H_N * H_N,   ab1 + task * H_N, hb1, w, lane);
    __syncthreads();
    {
        const float* W2 = aW2 + task * H_N * A_N;
        const float* b2 = ab2 + task * A_N;
        int r = tid >> 4, a = tid & 15;
        float acc = 0.0f;
#pragma unroll 4
        for (int i = 0; i < H_N; i += 4) {
            float4 hv = *reinterpret_cast<const float4*>(&hb1[r * H_N + i]);
            acc = fmaf(hv.x, W2[(i + 0) * A_N + a], acc);
            acc = fmaf(hv.y, W2[(i + 1) * A_N + a], acc);
            acc = fmaf(hv.z, W2[(i + 2) * A_N + a], acc);
            acc = fmaf(hv.w, W2[(i + 3) * A_N + a], acc);
        }
        acc += b2[a];
        if (r < nrows) out[(size_t)tidx[r] * A_N + a] = acc;
    }
    layer_block<OBS_N, true>(xs, cW0 + task * OBS_N * H_N, cb0 + task * H_N, hb0, w, lane);
    __syncthreads();
    layer_block<H_N,  true>(hb0, cW1 + task * H_N * H_N,  cb1 + task * H_N, hb1, w, lane);
    __syncthreads();
    {
        const float* W2 = cW2 + task * H_N;
        const float  b2 = cb2[task];
        int r = tid >> 4, sub = tid & 15;
        float acc = 0.0f;
#pragma unroll
        for (int k = 0; k < 32; k += 4) {
            int i = sub * 32 + k;
            float4 hv = *reinterpret_cast<const float4*>(&hb1[r * H_N + i]);
            float4 wv = *reinterpret_cast<const float4*>(&W2[i]);
            acc = fmaf(hv.x, wv.x, acc);
            acc = fmaf(hv.y, wv.y, acc);
            acc = fmaf(hv.z, wv.z, acc);
            acc = fmaf(hv.w, wv.w, acc);
        }
        acc += __shfl_xor(acc, 1);
        acc += __shfl_xor(acc, 2);
        acc += __shfl_xor(acc, 4);
        acc += __shfl_xor(acc, 8);
        if (sub == 0 && r < nrows) out[B_N * A_N + tidx[r]] = acc + b2;
    }
}

// ---------------------------------------------------------------------------
extern "C" void kernel_launch(void* const* d_in, const int* in_sizes, int n_in,
                              void* d_out, int out_size, void* d_ws, size_t ws_size,
                              hipStream_t stream)
{
    const float* x        = (const float*)d_in[0];
    const int*   task_ids = (const int*)  d_in[1];
    const float* aW0 = (const float*)d_in[2];
    const float* ab0 = (const float*)d_in[3];
    const float* aW1 = (const float*)d_in[4];
    const float* ab1 = (const float*)d_in[5];
    const float* aW2 = (const float*)d_in[6];
    const float* ab2 = (const float*)d_in[7];
    const float* cW0 = (const float*)d_in[8];
    const float* cb0 = (const float*)d_in[9];
    const float* cW1 = (const float*)d_in[10];
    const float* cb1 = (const float*)d_in[11];
    const float* cW2 = (const float*)d_in[12];
    const float* cb2 = (const float*)d_in[13];
    float* out = (float*)d_out;

    int* counts = (int*)d_ws;
    int* idx    = (int*)((char*)d_ws + IDX_OFF);

    hipMemsetAsync(counts, 0, T_N * sizeof(int), stream);
    bin_kernel<<<B_N / 256, 256, 0, stream>>>(task_ids, counts, idx);

    if (ws_size >= WS_NEED) {
        unsigned short* wpk = (unsigned short*)((char*)d_ws + W_PK_OFF);
        conv_pack<<<T_N * 48, 256, 0, stream>>>(aW0, aW1, cW0, cW1, wpk);
        moe_mfma_kernel<<<256, 512, 131584, stream>>>(
            x, counts, idx, wpk,
            ab0, ab1, aW2, ab2, cb0, cb1, cW2, cb2, out);
    } else {
        size_t lds_bytes = (size_t)(ROWS * OBS_N + 2 * ROWS * H_N) * sizeof(float);
        mlp_fallback<<<2 * 8 * 256, 256, lds_bytes, stream>>>(
            x, counts, idx,
            aW0, ab0, aW1, ab1, aW2, ab2,
            cW0, cb0, cW1, cb1, cW2, cb2, out);
    }
}

// Round 6
// 695.959 us; speedup vs baseline: 2.3108x; 2.3108x over previous
//
#include <hip/hip_runtime.h>

// Problem constants
#define B_N   16384
#define OBS_N 256
#define T_N   16
#define H_N   512
#define A_N   16

typedef __attribute__((ext_vector_type(8))) short  bf16x8;
typedef __attribute__((ext_vector_type(4))) float  f32x4;

// ---- workspace layout ----
// [0,64): counts | [1024, 1024+1MB): idx lists | [2MB, 2MB+48MB): packed weights
#define IDX_OFF   1024
#define W_PK_OFF  (2u * 1024u * 1024u)
// Packed elements per task (hi+lo interleaved per 1024-elem tile):
//   tile = [512 hi bf16][512 lo bf16] for one (16n x 32k) MFMA B-tile.
#define PK_A0     0
#define PK_A1     262144
#define PK_C0     786432
#define PK_C1     1048576
#define PK_TASK   1572864
#define WS_NEED   ((size_t)W_PK_OFF + (size_t)T_N * PK_TASK * 2u)   // 52,428,800 B

__device__ __forceinline__ unsigned short f2bf(float x) {
    unsigned u = __float_as_uint(x);
    u += 0x7FFFu + ((u >> 16) & 1u);
    return (unsigned short)(u >> 16);
}
__device__ __forceinline__ float bf2f(unsigned short h) {
    return __uint_as_float(((unsigned)h) << 16);
}
__device__ __forceinline__ float tanh_fast(float v) {
    return 1.0f - 2.0f / (__expf(2.0f * v) + 1.0f);
}

// ---------------------------------------------------------------------------
// Binning: sample indices by task.
// ---------------------------------------------------------------------------
__global__ void bin_kernel(const int* __restrict__ task_ids,
                           int* __restrict__ counts,
                           int* __restrict__ idx)
{
    int b = blockIdx.x * blockDim.x + threadIdx.x;
    if (b < B_N) {
        int t = task_ids[b];
        int p = atomicAdd(&counts[t], 1);
        idx[t * B_N + p] = b;
    }
}

// ---------------------------------------------------------------------------
// Weight conversion+pack: [T][K][512] f32 -> per-(16n x 32k) MFMA tiles.
// Tile tt = nt*(K/32)+ks holds 1024 bf16: [512 hi][512 lo], element order
// lane*8+j with lane = (n&15) + 16*((k&31)>>3), j = k&7 — exactly the
// 16x16x32 B-fragment order, so GEMM loads are 1 coalesced dwordx4 per frag.
// Block = one (task, seg, ks): stages 32x512 f32 (64 KB LDS), packs 32 tiles.
// ---------------------------------------------------------------------------
__global__ __launch_bounds__(256)
void conv_pack(const float* __restrict__ aW0, const float* __restrict__ aW1,
               const float* __restrict__ cW0, const float* __restrict__ cW1,
               unsigned short* __restrict__ wp)
{
    __shared__ float sf[32 * 512];
    const int bid = blockIdx.x;              // 16 tasks * 48
    const int t = bid / 48, s = bid % 48;
    const float* src; int K, ks, pk;
    if (s < 8)       { src = aW0; K = 256; ks = s;      pk = PK_A0; }
    else if (s < 24) { src = aW1; K = 512; ks = s - 8;  pk = PK_A1; }
    else if (s < 32) { src = cW0; K = 256; ks = s - 24; pk = PK_C0; }
    else             { src = cW1; K = 512; ks = s - 32; pk = PK_C1; }

    const int tid = threadIdx.x;
    const float* sp = src + ((size_t)t * K + (size_t)ks * 32) * 512;
    #pragma unroll
    for (int i = 0; i < 16; ++i) {
        int f = tid + i * 256;               // 4096 float4
        *(float4*)(sf + f * 4) = *(const float4*)(sp + f * 4);
    }
    __syncthreads();

    unsigned short* wt = wp + (size_t)t * PK_TASK + pk;
    const int KS = K / 32;
    #pragma unroll
    for (int u = 0; u < 8; ++u) {
        int p    = u * 256 + tid;            // (nt, lane) pairs: 32*64
        int nt   = p >> 6;
        int lane = p & 63;
        int ln   = lane & 15;
        int ko   = (lane >> 4) * 8;
        unsigned hi2[4], lo2[4];
        #pragma unroll
        for (int jj = 0; jj < 4; ++jj) {
            float v0 = sf[(ko + 2 * jj + 0) * 512 + nt * 16 + ln];
            float v1 = sf[(ko + 2 * jj + 1) * 512 + nt * 16 + ln];
            unsigned short h0 = f2bf(v0), h1 = f2bf(v1);
            unsigned short l0 = f2bf(v0 - bf2f(h0));
            unsigned short l1 = f2bf(v1 - bf2f(h1));
            hi2[jj] = (unsigned)h0 | ((unsigned)h1 << 16);
            lo2[jj] = (unsigned)l0 | ((unsigned)l1 << 16);
        }
        size_t base = (size_t)(nt * KS + ks) * 1024 + lane * 8;
        *(uint4*)(wt + base)       = make_uint4(hi2[0], hi2[1], hi2[2], hi2[3]);
        *(uint4*)(wt + base + 512) = make_uint4(lo2[0], lo2[1], lo2[2], lo2[3]);
    }
}

// ---------------------------------------------------------------------------
// GEMM pass engine. Block 512 thr (8 waves), 64 rows x 512 cols.
// Wave w owns cols [w*64, w*64+64) = tiles nt = w*4..w*4+3.
// A (activations) hi/lo in LDS, XOR-swizzled (byte ^= (row&7)<<4).
// B (weights) streamed coalesced from packed global via a depth-2 rolling
// prefetch ring (3 live B frags only — keeps VGPR pressure low; round-4's
// 4-buffer scheme spilled 1.09 GB to scratch).
// Pass LO=false: acc += Ah*Bh + Al*Bh (2 MFMA/tile).
// Pass LO=true : acc += Ah*Bl          (1 MFMA/tile).
// ---------------------------------------------------------------------------
template <int K, bool LO>
__device__ __forceinline__ void gemm_pass(const unsigned short* __restrict__ wseg,
                                          const char* __restrict__ ahb,
                                          const char* __restrict__ alb,
                                          int w, int lane, f32x4 acc[4][4])
{
    constexpr int KS = K / 32;
    const int ln  = lane & 15;
    const int lk  = (lane >> 4) * 8;
    const int swz = (ln & 7) << 4;
    const unsigned short* bp = wseg + (size_t)(w * 4) * KS * 1024 + lane * 8
                                    + (LO ? 512 : 0);
    int abase[4];
    #pragma unroll
    for (int m = 0; m < 4; ++m)
        abase[m] = ((m * 16 + ln) * K + lk) * 2;

    bf16x8 b0 = *(const bf16x8*)(bp);                        // unit (ct0,s0)
    bf16x8 b1 = *(const bf16x8*)(bp + (size_t)KS * 1024);    // unit (ct1,s0)
    #pragma unroll 1
    for (int s = 0; s < KS; ++s) {
        bf16x8 ah[4], al[4];
        #pragma unroll
        for (int m = 0; m < 4; ++m) {
            int ab = (abase[m] + s * 64) ^ swz;
            ah[m] = *(const bf16x8*)(ahb + ab);
        }
        if (!LO) {
            #pragma unroll
            for (int m = 0; m < 4; ++m) {
                int ab = (abase[m] + s * 64) ^ swz;
                al[m] = *(const bf16x8*)(alb + ab);
            }
        }
        #pragma unroll
        for (int ct = 0; ct < 4; ++ct) {
            int pct = ct + 2, ps = s;
            if (pct >= 4) { pct -= 4; ps = s + 1; }
            if (ps >= KS) { pct = 3; ps = KS - 1; }          // tail: reload last
            bf16x8 b2 = *(const bf16x8*)(bp + (size_t)(pct * KS + ps) * 1024);
            #pragma unroll
            for (int m = 0; m < 4; ++m)
                acc[m][ct] = __builtin_amdgcn_mfma_f32_16x16x32_bf16(ah[m], b0, acc[m][ct], 0, 0, 0);
            if (!LO) {
                #pragma unroll
                for (int m = 0; m < 4; ++m)
                    acc[m][ct] = __builtin_amdgcn_mfma_f32_16x16x32_bf16(al[m], b0, acc[m][ct], 0, 0, 0);
            }
            b0 = b1; b1 = b2;
        }
    }
}

__device__ __forceinline__ void zero_acc(f32x4 acc[4][4]) {
#pragma unroll
    for (int m = 0; m < 4; ++m)
#pragma unroll
        for (int ct = 0; ct < 4; ++ct)
            acc[m][ct] = (f32x4){0.f, 0.f, 0.f, 0.f};
}

// epilogue: tanh + split-bf16 -> next A LDS ([64][512] hi/lo, swizzled)
__device__ __forceinline__ void epi_tanh(f32x4 acc[4][4], const float* __restrict__ bias,
                                         char* ahb, char* alb, int w, int lane)
{
    const int q4 = (lane >> 4) * 4;
    const int ln = lane & 15;
#pragma unroll
    for (int ct = 0; ct < 4; ++ct) {
        int col = w * 64 + ct * 16 + ln;
        float b = bias[col];
#pragma unroll
        for (int m = 0; m < 4; ++m) {
#pragma unroll
            for (int q = 0; q < 4; ++q) {
                int row = m * 16 + q4 + q;
                float t = tanh_fast(acc[m][ct][q] + b);
                unsigned short h = f2bf(t);
                unsigned short l = f2bf(t - bf2f(h));
                int byte = ((row * 512 + col) * 2) ^ ((row & 7) << 4);
                *(unsigned short*)(ahb + byte) = h;
                *(unsigned short*)(alb + byte) = l;
            }
        }
    }
}

// epilogue: tanh -> fp32 h2 LDS ([64][512] f32, swizzled)
__device__ __forceinline__ void epi_h2(f32x4 acc[4][4], const float* __restrict__ bias,
                                       char* h2b, int w, int lane)
{
    const int q4 = (lane >> 4) * 4;
    const int ln = lane & 15;
#pragma unroll
    for (int ct = 0; ct < 4; ++ct) {
        int col = w * 64 + ct * 16 + ln;
        float b = bias[col];
#pragma unroll
        for (int m = 0; m < 4; ++m) {
#pragma unroll
            for (int q = 0; q < 4; ++q) {
                int row = m * 16 + q4 + q;
                float t = tanh_fast(acc[m][ct][q] + b);
                int byte = (row * 2048 + col * 4) ^ ((row & 7) << 4);
                *(float*)(h2b + byte) = t;
            }
        }
    }
}

// gather x rows -> xs hi/lo ([64][256] bf16, swizzled); 1 KB coalesced per instr
__device__ __forceinline__ void gather_xs(const float* __restrict__ x,
                                          const int* __restrict__ tidx_lds, int nrows,
                                          char* xhb, char* xlb, int tid)
{
#pragma unroll
    for (int kk = 0; kk < 8; ++kk) {
        int f   = tid + kk * 512;
        int row = f >> 6;
        int c4  = f & 63;
        int rr  = min(row, nrows - 1);
        int sid = tidx_lds[rr];
        float4 v = *(const float4*)(x + (size_t)sid * OBS_N + c4 * 4);
        unsigned short h0 = f2bf(v.x), h1 = f2bf(v.y), h2e = f2bf(v.z), h3 = f2bf(v.w);
        unsigned short l0 = f2bf(v.x - bf2f(h0)), l1 = f2bf(v.y - bf2f(h1));
        unsigned short l2 = f2bf(v.z - bf2f(h2e)), l3 = f2bf(v.w - bf2f(h3));
        uint2 hp = make_uint2((unsigned)h0 | ((unsigned)h1 << 16), (unsigned)h2e | ((unsigned)h3 << 16));
        uint2 lp = make_uint2((unsigned)l0 | ((unsigned)l1 << 16), (unsigned)l2 | ((unsigned)l3 << 16));
        int byte = ((row * OBS_N + c4 * 4) * 2) ^ ((row & 7) << 4);
        *(uint2*)(xhb + byte) = hp;
        *(uint2*)(xlb + byte) = lp;
    }
}

__device__ __forceinline__ void actor_head(const char* __restrict__ h2b,
                                           const float* __restrict__ W2,
                                           const float* __restrict__ b2,
                                           const int* __restrict__ tidx_lds, int nrows,
                                           float* __restrict__ out, int tid)
{
#pragma unroll
    for (int oo = 0; oo < 2; ++oo) {
        int o = tid + oo * 512;
        int r = o >> 4, a = o & 15;
        float acc = 0.f;
#pragma unroll 4
        for (int i = 0; i < H_N; i += 4) {
            int byte = (r * 2048 + i * 4) ^ ((r & 7) << 4);
            float4 hv = *(const float4*)(h2b + byte);
            acc = fmaf(hv.x, W2[(i + 0) * A_N + a], acc);
            acc = fmaf(hv.y, W2[(i + 1) * A_N + a], acc);
            acc = fmaf(hv.z, W2[(i + 2) * A_N + a], acc);
            acc = fmaf(hv.w, W2[(i + 3) * A_N + a], acc);
        }
        if (r < nrows)
            out[(size_t)tidx_lds[r] * A_N + a] = acc + b2[a];
    }
}

// critic head: lane stripe i = sub*4 + j*32 -> 8 subs x 4 banks = all 32 banks
__device__ __forceinline__ void critic_head(const char* __restrict__ h2b,
                                            const float* __restrict__ W2, float b2,
                                            const int* __restrict__ tidx_lds, int nrows,
                                            float* __restrict__ out, int tid)
{
    int r = tid >> 3, sub = tid & 7;
    float acc = 0.f;
#pragma unroll
    for (int j = 0; j < 16; ++j) {
        int i = sub * 4 + j * 32;
        int byte = (r * 2048 + i * 4) ^ ((r & 7) << 4);
        float4 hv = *(const float4*)(h2b + byte);
        float4 wv = *(const float4*)(W2 + i);
        acc = fmaf(hv.x, wv.x, acc);
        acc = fmaf(hv.y, wv.y, acc);
        acc = fmaf(hv.z, wv.z, acc);
        acc = fmaf(hv.w, wv.w, acc);
    }
    acc += __shfl_xor(acc, 1);
    acc += __shfl_xor(acc, 2);
    acc += __shfl_xor(acc, 4);
    if (sub == 0 && r < nrows)
        out[B_N * A_N + tidx_lds[r]] = acc + b2;
}

// LDS map (dynamic, 131,584 B):
//   [0,128K): union { xs_hi/h_hi | h2 f32 } with lo halves at +64K
//   [128K,+256): tidx
__global__ __launch_bounds__(512, 2)
void moe_mfma_kernel(const float* __restrict__ x,
                     const int* __restrict__ counts,
                     const int* __restrict__ idx,
                     const unsigned short* __restrict__ wp,
                     const float* __restrict__ ab0, const float* __restrict__ ab1,
                     const float* __restrict__ aW2, const float* __restrict__ ab2,
                     const float* __restrict__ cb0, const float* __restrict__ cb1,
                     const float* __restrict__ cW2, const float* __restrict__ cb2,
                     float* __restrict__ out)
{
    extern __shared__ char lds[];
    char* lo_half  = lds + 65536;
    int*  tidx_lds = (int*)(lds + 131072);

    const int bx   = blockIdx.x;
    const int task = bx & 15;
    const int slot = bx >> 4;               // 16 slots x 64 rows = 1024/sweep
    const int cnt  = counts[task];
    const int tid  = threadIdx.x;
    const int w    = tid >> 6;
    const int lane = tid & 63;

    const unsigned short* wt = wp + (size_t)task * PK_TASK;

    for (int r0 = slot * 64; r0 < cnt; r0 += 1024) {
        int nrows = min(64, cnt - r0);

        __syncthreads();                     // protect tidx/h2 across iters
        if (tid < 64) {
            int rr = min(tid, nrows - 1);
            tidx_lds[tid] = idx[task * B_N + r0 + rr];
        }
        __syncthreads();

        f32x4 acc[4][4];

        // ================= ACTOR =================
        gather_xs(x, tidx_lds, nrows, lds, lo_half, tid);
        __syncthreads();
        zero_acc(acc);
        gemm_pass<256, false>(wt + PK_A0, lds, lo_half, w, lane, acc);
        gemm_pass<256, true >(wt + PK_A0, lds, lo_half, w, lane, acc);
        __syncthreads();                     // all waves done reading xs
        epi_tanh(acc, ab0 + task * H_N, lds, lo_half, w, lane);
        __syncthreads();
        zero_acc(acc);
        gemm_pass<512, false>(wt + PK_A1, lds, lo_half, w, lane, acc);
        gemm_pass<512, true >(wt + PK_A1, lds, lo_half, w, lane, acc);
        __syncthreads();                     // done reading h
        epi_h2(acc, ab1 + task * H_N, lds, w, lane);
        __syncthreads();
        actor_head(lds, aW2 + (size_t)task * H_N * A_N, ab2 + task * A_N,
                   tidx_lds, nrows, out, tid);
        __syncthreads();                     // heads done reading h2

        // ================= CRITIC =================
        gather_xs(x, tidx_lds, nrows, lds, lo_half, tid);
        __syncthreads();
        zero_acc(acc);
        gemm_pass<256, false>(wt + PK_C0, lds, lo_half, w, lane, acc);
        gemm_pass<256, true >(wt + PK_C0, lds, lo_half, w, lane, acc);
        __syncthreads();
        epi_tanh(acc, cb0 + task * H_N, lds, lo_half, w, lane);
        __syncthreads();
        zero_acc(acc);
        gemm_pass<512, false>(wt + PK_C1, lds, lo_half, w, lane, acc);
        gemm_pass<512, true >(wt + PK_C1, lds, lo_half, w, lane, acc);
        __syncthreads();
        epi_h2(acc, cb1 + task * H_N, lds, w, lane);
        __syncthreads();
        critic_head(lds, cW2 + (size_t)task * H_N, cb2[task],
                    tidx_lds, nrows, out, tid);
    }
}

// ===========================================================================
// Fallback (fp32 VALU) if ws_size can't hold packed weights.
// ===========================================================================
#define ROWS 16
template <int IN, bool TANH>
__device__ __forceinline__ void layer_block(const float* __restrict__ in_lds,
                                            const float* __restrict__ W,
                                            const float* __restrict__ bias,
                                            float* __restrict__ out_lds,
                                            int w, int lane)
{
#pragma unroll
    for (int cgi = 0; cgi < 2; ++cgi) {
        const int c = (w + 4 * cgi) * 64 + lane;
        float acc[ROWS];
#pragma unroll
        for (int r = 0; r < ROWS; ++r) acc[r] = 0.0f;
        const float* Wc = W + c;
#pragma unroll 2
        for (int i = 0; i < IN; i += 4) {
            float w0 = Wc[(i + 0) * H_N];
            float w1 = Wc[(i + 1) * H_N];
            float w2 = Wc[(i + 2) * H_N];
            float w3 = Wc[(i + 3) * H_N];
#pragma unroll
            for (int r = 0; r < ROWS; ++r) {
                float4 xv = *reinterpret_cast<const float4*>(&in_lds[r * IN + i]);
                acc[r] = fmaf(xv.x, w0, acc[r]);
                acc[r] = fmaf(xv.y, w1, acc[r]);
                acc[r] = fmaf(xv.z, w2, acc[r]);
                acc[r] = fmaf(xv.w, w3, acc[r]);
            }
        }
        float bb = bias[c];
#pragma unroll
        for (int r = 0; r < ROWS; ++r) {
            float v = acc[r] + bb;
            if (TANH) v = 1.0f - 2.0f / (__expf(2.0f * v) + 1.0f);
            out_lds[r * H_N + c] = v;
        }
    }
}

__global__ __launch_bounds__(256, 2)
void mlp_fallback(const float* __restrict__ x,
                  const int* __restrict__ counts,
                  const int* __restrict__ idx,
                  const float* __restrict__ aW0, const float* __restrict__ ab0,
                  const float* __restrict__ aW1, const float* __restrict__ ab1,
                  const float* __restrict__ aW2, const float* __restrict__ ab2,
                  const float* __restrict__ cW0, const float* __restrict__ cb0,
                  const float* __restrict__ cW1, const float* __restrict__ cb1,
                  const float* __restrict__ cW2, const float* __restrict__ cb2,
                  float* __restrict__ out)
{
    extern __shared__ float flds[];
    float* xs  = flds;
    float* hb0 = flds + ROWS * OBS_N;
    float* hb1 = hb0 + ROWS * H_N;

    const int bx    = blockIdx.x;
    const int phase = bx >> 11;
    const int task  = (bx & 7) + (phase << 3);
    const int tile  = (bx >> 3) & 255;
    const int cnt   = counts[task];
    const int r0    = tile * ROWS;
    if (r0 >= cnt) return;
    const int nrows = min(ROWS, cnt - r0);
    const int tid   = threadIdx.x;
    const int lane  = tid & 63;
    const int w     = tid >> 6;
    const int* tidx = idx + task * B_N + r0;

    {
        const float4* x4  = reinterpret_cast<const float4*>(x);
        float4*       xs4 = reinterpret_cast<float4*>(xs);
#pragma unroll
        for (int k = 0; k < 4; ++k) {
            int f = tid + k * 256;
            int r = f >> 6, c4 = f & 63;
            int rr = (r < nrows) ? r : (nrows - 1);
            xs4[f] = x4[(size_t)tidx[rr] * (OBS_N / 4) + c4];
        }
    }
    __syncthreads();
    layer_block<OBS_N, true>(xs,  aW0 + task * OBS_N * H_N, ab0 + task * H_N, hb0, w, lane);
    __syncthreads();
    layer_block<H_N,  true>(hb0, aW1 + task * H_N * H_N,   ab1 + task * H_N, hb1, w, lane);
    __syncthreads();
    {
        const float* W2 = aW2 + task * H_N * A_N;
        const float* b2 = ab2 + task * A_N;
        int r = tid >> 4, a = tid & 15;
        float acc = 0.0f;
#pragma unroll 4
        for (int i = 0; i < H_N; i += 4) {
            float4 hv = *reinterpret_cast<const float4*>(&hb1[r * H_N + i]);
            acc = fmaf(hv.x, W2[(i + 0) * A_N + a], acc);
            acc = fmaf(hv.y, W2[(i + 1) * A_N + a], acc);
            acc = fmaf(hv.z, W2[(i + 2) * A_N + a], acc);
            acc = fmaf(hv.w, W2[(i + 3) * A_N + a], acc);
        }
        acc += b2[a];
        if (r < nrows) out[(size_t)tidx[r] * A_N + a] = acc;
    }
    layer_block<OBS_N, true>(xs, cW0 + task * OBS_N * H_N, cb0 + task * H_N, hb0, w, lane);
    __syncthreads();
    layer_block<H_N,  true>(hb0, cW1 + task * H_N * H_N,  cb1 + task * H_N, hb1, w, lane);
    __syncthreads();
    {
        const float* W2 = cW2 + task * H_N;
        const float  b2 = cb2[task];
        int r = tid >> 4, sub = tid & 15;
        float acc = 0.0f;
#pragma unroll
        for (int k = 0; k < 32; k += 4) {
            int i = sub * 32 + k;
            float4 hv = *reinterpret_cast<const float4*>(&hb1[r * H_N + i]);
            float4 wv = *reinterpret_cast<const float4*>(&W2[i]);
            acc = fmaf(hv.x, wv.x, acc);
            acc = fmaf(hv.y, wv.y, acc);
            acc = fmaf(hv.z, wv.z, acc);
            acc = fmaf(hv.w, wv.w, acc);
        }
        acc += __shfl_xor(acc, 1);
        acc += __shfl_xor(acc, 2);
        acc += __shfl_xor(acc, 4);
        acc += __shfl_xor(acc, 8);
        if (sub == 0 && r < nrows) out[B_N * A_N + tidx[r]] = acc + b2;
    }
}

// ---------------------------------------------------------------------------
extern "C" void kernel_launch(void* const* d_in, const int* in_sizes, int n_in,
                              void* d_out, int out_size, void* d_ws, size_t ws_size,
                              hipStream_t stream)
{
    const float* x        = (const float*)d_in[0];
    const int*   task_ids = (const int*)  d_in[1];
    const float* aW0 = (const float*)d_in[2];
    const float* ab0 = (const float*)d_in[3];
    const float* aW1 = (const float*)d_in[4];
    const float* ab1 = (const float*)d_in[5];
    const float* aW2 = (const float*)d_in[6];
    const float* ab2 = (const float*)d_in[7];
    const float* cW0 = (const float*)d_in[8];
    const float* cb0 = (const float*)d_in[9];
    const float* cW1 = (const float*)d_in[10];
    const float* cb1 = (const float*)d_in[11];
    const float* cW2 = (const float*)d_in[12];
    const float* cb2 = (const float*)d_in[13];
    float* out = (float*)d_out;

    int* counts = (int*)d_ws;
    int* idx    = (int*)((char*)d_ws + IDX_OFF);

    hipMemsetAsync(counts, 0, T_N * sizeof(int), stream);
    bin_kernel<<<B_N / 256, 256, 0, stream>>>(task_ids, counts, idx);

    if (ws_size >= WS_NEED) {
        unsigned short* wpk = (unsigned short*)((char*)d_ws + W_PK_OFF);
        conv_pack<<<T_N * 48, 256, 0, stream>>>(aW0, aW1, cW0, cW1, wpk);
        moe_mfma_kernel<<<256, 512, 131584, stream>>>(
            x, counts, idx, wpk,
            ab0, ab1, aW2, ab2, cb0, cb1, cW2, cb2, out);
    } else {
        size_t lds_bytes = (size_t)(ROWS * OBS_N + 2 * ROWS * H_N) * sizeof(float);
        mlp_fallback<<<2 * 8 * 256, 256, lds_bytes, stream>>>(
            x, counts, idx,
            aW0, ab0, aW1, ab1, aW2, ab2,
            cW0, cb0, cW1, cb1, cW2, cb2, out);
    }
}

// Round 7
// 639.203 us; speedup vs baseline: 2.5160x; 1.0888x over previous
//
#include <hip/hip_runtime.h>

// Problem constants
#define B_N   16384
#define OBS_N 256
#define T_N   16
#define H_N   512
#define A_N   16

typedef __attribute__((ext_vector_type(8))) short  bf16x8;
typedef __attribute__((ext_vector_type(4))) float  f32x4;

// ---- workspace layout ----
// [0,64): counts | [1024, 1024+1MB): idx lists | [2MB, 2MB+48MB): packed weights
#define IDX_OFF   1024
#define W_PK_OFF  (2u * 1024u * 1024u)
// Packed elements per task: tile = [512 hi bf16][512 lo bf16] per (16n x 32k).
#define PK_A0     0
#define PK_A1     262144
#define PK_C0     786432
#define PK_C1     1048576
#define PK_TASK   1572864
#define WS_NEED   ((size_t)W_PK_OFF + (size_t)T_N * PK_TASK * 2u)   // 52,428,800 B

__device__ __forceinline__ unsigned short f2bf(float x) {
    unsigned u = __float_as_uint(x);
    u += 0x7FFFu + ((u >> 16) & 1u);
    return (unsigned short)(u >> 16);
}
__device__ __forceinline__ float bf2f(unsigned short h) {
    return __uint_as_float(((unsigned)h) << 16);
}
__device__ __forceinline__ float tanh_fast(float v) {
    return 1.0f - 2.0f / (__expf(2.0f * v) + 1.0f);
}

// ---------------------------------------------------------------------------
// Binning: sample indices by task.
// ---------------------------------------------------------------------------
__global__ void bin_kernel(const int* __restrict__ task_ids,
                           int* __restrict__ counts,
                           int* __restrict__ idx)
{
    int b = blockIdx.x * blockDim.x + threadIdx.x;
    if (b < B_N) {
        int t = task_ids[b];
        int p = atomicAdd(&counts[t], 1);
        idx[t * B_N + p] = b;
    }
}

// ---------------------------------------------------------------------------
// Weight conversion+pack (unchanged from round 6 — verified correct):
// [T][K][512] f32 -> (16n x 32k) MFMA B-tiles, [512 hi][512 lo] per tile,
// element order = exact 16x16x32 B-fragment order (lane*8+j).
// ---------------------------------------------------------------------------
__global__ __launch_bounds__(256)
void conv_pack(const float* __restrict__ aW0, const float* __restrict__ aW1,
               const float* __restrict__ cW0, const float* __restrict__ cW1,
               unsigned short* __restrict__ wp)
{
    __shared__ float sf[32 * 512];
    const int bid = blockIdx.x;              // 16 tasks * 48
    const int t = bid / 48, s = bid % 48;
    const float* src; int K, ks, pk;
    if (s < 8)       { src = aW0; K = 256; ks = s;      pk = PK_A0; }
    else if (s < 24) { src = aW1; K = 512; ks = s - 8;  pk = PK_A1; }
    else if (s < 32) { src = cW0; K = 256; ks = s - 24; pk = PK_C0; }
    else             { src = cW1; K = 512; ks = s - 32; pk = PK_C1; }

    const int tid = threadIdx.x;
    const float* sp = src + ((size_t)t * K + (size_t)ks * 32) * 512;
    #pragma unroll
    for (int i = 0; i < 16; ++i) {
        int f = tid + i * 256;               // 4096 float4
        *(float4*)(sf + f * 4) = *(const float4*)(sp + f * 4);
    }
    __syncthreads();

    unsigned short* wt = wp + (size_t)t * PK_TASK + pk;
    const int KS = K / 32;
    #pragma unroll
    for (int u = 0; u < 8; ++u) {
        int p    = u * 256 + tid;            // (nt, lane) pairs: 32*64
        int nt   = p >> 6;
        int lane = p & 63;
        int ln   = lane & 15;
        int ko   = (lane >> 4) * 8;
        unsigned hi2[4], lo2[4];
        #pragma unroll
        for (int jj = 0; jj < 4; ++jj) {
            float v0 = sf[(ko + 2 * jj + 0) * 512 + nt * 16 + ln];
            float v1 = sf[(ko + 2 * jj + 1) * 512 + nt * 16 + ln];
            unsigned short h0 = f2bf(v0), h1 = f2bf(v1);
            unsigned short l0 = f2bf(v0 - bf2f(h0));
            unsigned short l1 = f2bf(v1 - bf2f(h1));
            hi2[jj] = (unsigned)h0 | ((unsigned)h1 << 16);
            lo2[jj] = (unsigned)l0 | ((unsigned)l1 << 16);
        }
        size_t base = (size_t)(nt * KS + ks) * 1024 + lane * 8;
        *(uint4*)(wt + base)       = make_uint4(hi2[0], hi2[1], hi2[2], hi2[3]);
        *(uint4*)(wt + base + 512) = make_uint4(lo2[0], lo2[1], lo2[2], lo2[3]);
    }
}

// ---------------------------------------------------------------------------
// GEMM: block tile 32 rows x 512 cols, 512 thr / 8 waves.
// Wave w owns cols [w*64,w*64+64) (tiles nt=w*4..w*4+3), ALL 32 rows ->
// acc[2][4] = 32 regs (round-6's acc[4][4]=64 caused the 128-VGPR spill).
// A hi/lo in LDS (XOR-swizzled byte ^= (row&7)<<4). B streamed from packed
// global with depth-1 prefetch. C += Ah*Bh + Al*Bh + Ah*Bl.
// ---------------------------------------------------------------------------
template <int K>
__device__ __forceinline__ void gemm32(const unsigned short* __restrict__ wseg,
                                       const char* __restrict__ ahb,
                                       const char* __restrict__ alb,
                                       int w, int lane, f32x4 acc[2][4])
{
    constexpr int KS = K / 32;
    const int ln  = lane & 15;
    const int lk  = (lane >> 4) * 8;
    const int swz = (ln & 7) << 4;
    const unsigned short* bp = wseg + (size_t)(w * 4) * KS * 1024 + lane * 8;
    int abase[2];
    abase[0] = (ln * K + lk) * 2;
    abase[1] = ((16 + ln) * K + lk) * 2;

    bf16x8 bh[4], bl[4], nh[4], nl[4];
    #pragma unroll
    for (int ct = 0; ct < 4; ++ct) {
        const unsigned short* q = bp + (size_t)(ct * KS) * 1024;
        bh[ct] = *(const bf16x8*)q;
        bl[ct] = *(const bf16x8*)(q + 512);
    }
    #pragma unroll 1
    for (int s = 0; s < KS; ++s) {
        const int sp = (s + 1 < KS) ? s + 1 : s;
        #pragma unroll
        for (int ct = 0; ct < 4; ++ct) {
            const unsigned short* q = bp + (size_t)(ct * KS + sp) * 1024;
            nh[ct] = *(const bf16x8*)q;
            nl[ct] = *(const bf16x8*)(q + 512);
        }
        bf16x8 ah[2], al[2];
        #pragma unroll
        for (int m = 0; m < 2; ++m) {
            int ab = (abase[m] + s * 64) ^ swz;
            ah[m] = *(const bf16x8*)(ahb + ab);
            al[m] = *(const bf16x8*)(alb + ab);
        }
        #pragma unroll
        for (int m = 0; m < 2; ++m) {
            #pragma unroll
            for (int ct = 0; ct < 4; ++ct) {
                acc[m][ct] = __builtin_amdgcn_mfma_f32_16x16x32_bf16(ah[m], bh[ct], acc[m][ct], 0, 0, 0);
                acc[m][ct] = __builtin_amdgcn_mfma_f32_16x16x32_bf16(al[m], bh[ct], acc[m][ct], 0, 0, 0);
                acc[m][ct] = __builtin_amdgcn_mfma_f32_16x16x32_bf16(ah[m], bl[ct], acc[m][ct], 0, 0, 0);
            }
        }
        #pragma unroll
        for (int ct = 0; ct < 4; ++ct) { bh[ct] = nh[ct]; bl[ct] = nl[ct]; }
    }
}

__device__ __forceinline__ void zero_acc(f32x4 acc[2][4]) {
#pragma unroll
    for (int m = 0; m < 2; ++m)
#pragma unroll
        for (int ct = 0; ct < 4; ++ct)
            acc[m][ct] = (f32x4){0.f, 0.f, 0.f, 0.f};
}

// epilogue: tanh + split-bf16 -> h LDS ([32][512] hi/lo, swizzled)
__device__ __forceinline__ void epi_tanh(f32x4 acc[2][4], const float* __restrict__ bias,
                                         char* hhb, char* hlb, int w, int lane)
{
    const int q4 = (lane >> 4) * 4;
    const int ln = lane & 15;
#pragma unroll
    for (int ct = 0; ct < 4; ++ct) {
        int col = w * 64 + ct * 16 + ln;
        float b = bias[col];
#pragma unroll
        for (int m = 0; m < 2; ++m) {
#pragma unroll
            for (int q = 0; q < 4; ++q) {
                int row = m * 16 + q4 + q;
                float t = tanh_fast(acc[m][ct][q] + b);
                unsigned short h = f2bf(t);
                unsigned short l = f2bf(t - bf2f(h));
                int byte = ((row * 512 + col) * 2) ^ ((row & 7) << 4);
                *(unsigned short*)(hhb + byte) = h;
                *(unsigned short*)(hlb + byte) = l;
            }
        }
    }
}

// epilogue: tanh -> fp32 h2 LDS ([32][512] f32, swizzled)
__device__ __forceinline__ void epi_h2(f32x4 acc[2][4], const float* __restrict__ bias,
                                       char* h2b, int w, int lane)
{
    const int q4 = (lane >> 4) * 4;
    const int ln = lane & 15;
#pragma unroll
    for (int ct = 0; ct < 4; ++ct) {
        int col = w * 64 + ct * 16 + ln;
        float b = bias[col];
#pragma unroll
        for (int m = 0; m < 2; ++m) {
#pragma unroll
            for (int q = 0; q < 4; ++q) {
                int row = m * 16 + q4 + q;
                float t = tanh_fast(acc[m][ct][q] + b);
                int byte = (row * 2048 + col * 4) ^ ((row & 7) << 4);
                *(float*)(h2b + byte) = t;
            }
        }
    }
}

// LDS map (dynamic, 163,840 B = full 160 KB; all regions DISJOINT):
//   xs_hi [0,16K)  xs_lo [16K,32K)   : [32][256] bf16
//   h_hi [32K,64K) h_lo [64K,96K)    : [32][512] bf16
//   h2   [96K,160K)                  : [32][512] f32
__global__ __launch_bounds__(512, 2)
void moe_mfma32(const float* __restrict__ x,
                const int* __restrict__ counts,
                const int* __restrict__ idx,
                const unsigned short* __restrict__ wp,
                const float* __restrict__ ab0, const float* __restrict__ ab1,
                const float* __restrict__ aW2, const float* __restrict__ ab2,
                const float* __restrict__ cb0, const float* __restrict__ cb1,
                const float* __restrict__ cW2, const float* __restrict__ cb2,
                float* __restrict__ out)
{
    extern __shared__ char lds[];
    char* xs_hi = lds;
    char* xs_lo = lds + 16384;
    char* h_hi  = lds + 32768;
    char* h_lo  = lds + 65536;
    char* h2b   = lds + 98304;

    const int bx   = blockIdx.x;
    const int xcd  = bx & 7;
    const int slot = bx >> 3;               // 0..31 ; 32 slots x 32 rows = 1024/sweep
    const int tid  = threadIdx.x;
    const int w    = tid >> 6;
    const int lane = tid & 63;

    // Two phases: each XCD works ONE task at a time -> 3 MB weight set fits 4 MB L2.
    #pragma unroll 1
    for (int p = 0; p < 2; ++p) {
        const int task = xcd + 8 * p;
        const int cnt  = counts[task];
        const unsigned short* wt  = wp + (size_t)task * PK_TASK;
        const int*            tix = idx + task * B_N;

        #pragma unroll 1
        for (int r0 = slot * 32; r0 < cnt; r0 += 1024) {
            const int nrows = min(32, cnt - r0);

            // ---- gather x rows -> xs hi/lo (prev iter's h2 readers untouched) ----
            #pragma unroll
            for (int k = 0; k < 4; ++k) {
                int f   = tid + k * 512;        // 0..2047 : 32 rows x 64 float4
                int row = f >> 6;
                int c4  = f & 63;
                int sid = tix[r0 + min(row, nrows - 1)];
                float4 v = *(const float4*)(x + (size_t)sid * OBS_N + c4 * 4);
                unsigned short e0 = f2bf(v.x), e1 = f2bf(v.y), e2 = f2bf(v.z), e3 = f2bf(v.w);
                unsigned short g0 = f2bf(v.x - bf2f(e0)), g1 = f2bf(v.y - bf2f(e1));
                unsigned short g2 = f2bf(v.z - bf2f(e2)), g3 = f2bf(v.w - bf2f(e3));
                uint2 hp = make_uint2((unsigned)e0 | ((unsigned)e1 << 16), (unsigned)e2 | ((unsigned)e3 << 16));
                uint2 lp = make_uint2((unsigned)g0 | ((unsigned)g1 << 16), (unsigned)g2 | ((unsigned)g3 << 16));
                int byte = ((row * OBS_N + c4 * 4) * 2) ^ ((row & 7) << 4);
                *(uint2*)(xs_hi + byte) = hp;
                *(uint2*)(xs_lo + byte) = lp;
            }
            __syncthreads();                     // xs ready (also fences prev iter)

            f32x4 acc[2][4];

            // ================= ACTOR =================
            zero_acc(acc);
            gemm32<256>(wt + PK_A0, xs_hi, xs_lo, w, lane, acc);
            epi_tanh(acc, ab0 + task * H_N, h_hi, h_lo, w, lane);  // h disjoint from xs
            __syncthreads();                     // h ready
            zero_acc(acc);
            gemm32<512>(wt + PK_A1, h_hi, h_lo, w, lane, acc);
            epi_h2(acc, ab1 + task * H_N, h2b, w, lane);           // h2 disjoint from h
            __syncthreads();                     // h2 ready; all done reading h
            {   // actor head: 32 rows x 16 logits = 512 outputs, one per thread
                const float* W2 = aW2 + (size_t)task * H_N * A_N;
                int r = tid >> 4, a = tid & 15;
                float s = 0.f;
                #pragma unroll 4
                for (int i = 0; i < H_N; i += 4) {
                    int byte = (r * 2048 + i * 4) ^ ((r & 7) << 4);
                    float4 hv = *(const float4*)(h2b + byte);
                    s = fmaf(hv.x, W2[(i + 0) * A_N + a], s);
                    s = fmaf(hv.y, W2[(i + 1) * A_N + a], s);
                    s = fmaf(hv.z, W2[(i + 2) * A_N + a], s);
                    s = fmaf(hv.w, W2[(i + 3) * A_N + a], s);
                }
                if (r < nrows)
                    out[(size_t)tix[r0 + r] * A_N + a] = s + ab2[task * A_N + a];
            }

            // ================= CRITIC ================= (xs still intact in LDS)
            zero_acc(acc);
            gemm32<256>(wt + PK_C0, xs_hi, xs_lo, w, lane, acc);
            epi_tanh(acc, cb0 + task * H_N, h_hi, h_lo, w, lane);  // h free since h2-sync
            __syncthreads();                     // h ready; all done with actor head
            zero_acc(acc);
            gemm32<512>(wt + PK_C1, h_hi, h_lo, w, lane, acc);
            epi_h2(acc, cb1 + task * H_N, h2b, w, lane);           // h2 free (post-sync)
            __syncthreads();                     // h2 ready
            {   // critic head: r = tid>>4 (32 rows), sub = tid&15, i = j*64+sub*4
                const float* W2 = cW2 + (size_t)task * H_N;
                int r = tid >> 4, sub = tid & 15;
                float s = 0.f;
                #pragma unroll
                for (int j = 0; j < 8; ++j) {
                    int i = j * 64 + sub * 4;
                    int byte = (r * 2048 + i * 4) ^ ((r & 7) << 4);
                    float4 hv = *(const float4*)(h2b + byte);
                    float4 wv = *(const float4*)(W2 + i);
                    s = fmaf(hv.x, wv.x, s);
                    s = fmaf(hv.y, wv.y, s);
                    s = fmaf(hv.z, wv.z, s);
                    s = fmaf(hv.w, wv.w, s);
                }
                s += __shfl_xor(s, 1);
                s += __shfl_xor(s, 2);
                s += __shfl_xor(s, 4);
                s += __shfl_xor(s, 8);
                if (sub == 0 && r < nrows)
                    out[B_N * A_N + tix[r0 + r]] = s + cb2[task];
            }
            // next iter's first write is xs (disjoint from h2) then a sync ✓
        }
    }
}

// ===========================================================================
// Fallback (fp32 VALU) if ws_size can't hold packed weights.
// ===========================================================================
#define ROWS 16
template <int IN, bool TANH>
__device__ __forceinline__ void layer_block(const float* __restrict__ in_lds,
                                            const float* __restrict__ W,
                                            const float* __restrict__ bias,
                                            float* __restrict__ out_lds,
                                            int w, int lane)
{
#pragma unroll
    for (int cgi = 0; cgi < 2; ++cgi) {
        const int c = (w + 4 * cgi) * 64 + lane;
        float acc[ROWS];
#pragma unroll
        for (int r = 0; r < ROWS; ++r) acc[r] = 0.0f;
        const float* Wc = W + c;
#pragma unroll 2
        for (int i = 0; i < IN; i += 4) {
            float w0 = Wc[(i + 0) * H_N];
            float w1 = Wc[(i + 1) * H_N];
            float w2 = Wc[(i + 2) * H_N];
            float w3 = Wc[(i + 3) * H_N];
#pragma unroll
            for (int r = 0; r < ROWS; ++r) {
                float4 xv = *reinterpret_cast<const float4*>(&in_lds[r * IN + i]);
                acc[r] = fmaf(xv.x, w0, acc[r]);
                acc[r] = fmaf(xv.y, w1, acc[r]);
                acc[r] = fmaf(xv.z, w2, acc[r]);
                acc[r] = fmaf(xv.w, w3, acc[r]);
            }
        }
        float bb = bias[c];
#pragma unroll
        for (int r = 0; r < ROWS; ++r) {
            float v = acc[r] + bb;
            if (TANH) v = 1.0f - 2.0f / (__expf(2.0f * v) + 1.0f);
            out_lds[r * H_N + c] = v;
        }
    }
}

__global__ __launch_bounds__(256, 2)
void mlp_fallback(const float* __restrict__ x,
                  const int* __restrict__ counts,
                  const int* __restrict__ idx,
                  const float* __restrict__ aW0, const float* __restrict__ ab0,
                  const float* __restrict__ aW1, const float* __restrict__ ab1,
                  const float* __restrict__ aW2, const float* __restrict__ ab2,
                  const float* __restrict__ cW0, const float* __restrict__ cb0,
                  const float* __restrict__ cW1, const float* __restrict__ cb1,
                  const float* __restrict__ cW2, const float* __restrict__ cb2,
                  float* __restrict__ out)
{
    extern __shared__ float flds[];
    float* xs  = flds;
    float* hb0 = flds + ROWS * OBS_N;
    float* hb1 = hb0 + ROWS * H_N;

    const int bx    = blockIdx.x;
    const int phase = bx >> 11;
    const int task  = (bx & 7) + (phase << 3);
    const int tile  = (bx >> 3) & 255;
    const int cnt   = counts[task];
    const int r0    = tile * ROWS;
    if (r0 >= cnt) return;
    const int nrows = min(ROWS, cnt - r0);
    const int tid   = threadIdx.x;
    const int lane  = tid & 63;
    const int w     = tid >> 6;
    const int* tidx = idx + task * B_N + r0;

    {
        const float4* x4  = reinterpret_cast<const float4*>(x);
        float4*       xs4 = reinterpret_cast<float4*>(xs);
#pragma unroll
        for (int k = 0; k < 4; ++k) {
            int f = tid + k * 256;
            int r = f >> 6, c4 = f & 63;
            int rr = (r < nrows) ? r : (nrows - 1);
            xs4[f] = x4[(size_t)tidx[rr] * (OBS_N / 4) + c4];
        }
    }
    __syncthreads();
    layer_block<OBS_N, true>(xs,  aW0 + task * OBS_N * H_N, ab0 + task * H_N, hb0, w, lane);
    __syncthreads();
    layer_block<H_N,  true>(hb0, aW1 + task * H_N * H_N,   ab1 + task * H_N, hb1, w, lane);
    __syncthreads();
    {
        const float* W2 = aW2 + task * H_N * A_N;
        const float* b2 = ab2 + task * A_N;
        int r = tid >> 4, a = tid & 15;
        float acc = 0.0f;
#pragma unroll 4
        for (int i = 0; i < H_N; i += 4) {
            float4 hv = *reinterpret_cast<const float4*>(&hb1[r * H_N + i]);
            acc = fmaf(hv.x, W2[(i + 0) * A_N + a], acc);
            acc = fmaf(hv.y, W2[(i + 1) * A_N + a], acc);
            acc = fmaf(hv.z, W2[(i + 2) * A_N + a], acc);
            acc = fmaf(hv.w, W2[(i + 3) * A_N + a], acc);
        }
        acc += b2[a];
        if (r < nrows) out[(size_t)tidx[r] * A_N + a] = acc;
    }
    layer_block<OBS_N, true>(xs, cW0 + task * OBS_N * H_N, cb0 + task * H_N, hb0, w, lane);
    __syncthreads();
    layer_block<H_N,  true>(hb0, cW1 + task * H_N * H_N,  cb1 + task * H_N, hb1, w, lane);
    __syncthreads();
    {
        const float* W2 = cW2 + task * H_N;
        const float  b2 = cb2[task];
        int r = tid >> 4, sub = tid & 15;
        float acc = 0.0f;
#pragma unroll
        for (int k = 0; k < 32; k += 4) {
            int i = sub * 32 + k;
            float4 hv = *reinterpret_cast<const float4*>(&hb1[r * H_N + i]);
            float4 wv = *reinterpret_cast<const float4*>(&W2[i]);
            acc = fmaf(hv.x, wv.x, acc);
            acc = fmaf(hv.y, wv.y, acc);
            acc = fmaf(hv.z, wv.z, acc);
            acc = fmaf(hv.w, wv.w, acc);
        }
        acc += __shfl_xor(acc, 1);
        acc += __shfl_xor(acc, 2);
        acc += __shfl_xor(acc, 4);
        acc += __shfl_xor(acc, 8);
        if (sub == 0 && r < nrows) out[B_N * A_N + tidx[r]] = acc + b2;
    }
}

// ---------------------------------------------------------------------------
extern "C" void kernel_launch(void* const* d_in, const int* in_sizes, int n_in,
                              void* d_out, int out_size, void* d_ws, size_t ws_size,
                              hipStream_t stream)
{
    const float* x        = (const float*)d_in[0];
    const int*   task_ids = (const int*)  d_in[1];
    const float* aW0 = (const float*)d_in[2];
    const float* ab0 = (const float*)d_in[3];
    const float* aW1 = (const float*)d_in[4];
    const float* ab1 = (const float*)d_in[5];
    const float* aW2 = (const float*)d_in[6];
    const float* ab2 = (const float*)d_in[7];
    const float* cW0 = (const float*)d_in[8];
    const float* cb0 = (const float*)d_in[9];
    const float* cW1 = (const float*)d_in[10];
    const float* cb1 = (const float*)d_in[11];
    const float* cW2 = (const float*)d_in[12];
    const float* cb2 = (const float*)d_in[13];
    float* out = (float*)d_out;

    int* counts = (int*)d_ws;
    int* idx    = (int*)((char*)d_ws + IDX_OFF);

    hipMemsetAsync(counts, 0, T_N * sizeof(int), stream);
    bin_kernel<<<B_N / 256, 256, 0, stream>>>(task_ids, counts, idx);

    if (ws_size >= WS_NEED) {
        unsigned short* wpk = (unsigned short*)((char*)d_ws + W_PK_OFF);
        conv_pack<<<T_N * 48, 256, 0, stream>>>(aW0, aW1, cW0, cW1, wpk);
        moe_mfma32<<<256, 512, 163840, stream>>>(
            x, counts, idx, wpk,
            ab0, ab1, aW2, ab2, cb0, cb1, cW2, cb2, out);
    } else {
        size_t lds_bytes = (size_t)(ROWS * OBS_N + 2 * ROWS * H_N) * sizeof(float);
        mlp_fallback<<<2 * 8 * 256, 256, lds_bytes, stream>>>(
            x, counts, idx,
            aW0, ab0, aW1, ab1, aW2, ab2,
            cW0, cb0, cW1, cb1, cW2, cb2, out);
    }
}